// Round 5
// baseline (3671.045 us; speedup 1.0000x reference)
//
#include <hip/hip_runtime.h>

// PathDecoder: B=256, L=192, H=320, E=128, V=27000, T=8
constexpr int Bn = 256;
constexpr int Ln = 192;
constexpr int Hn = 320;
constexpr int En = 128;
constexpr int Vn = 27000;
constexpr int Tn = 8;
constexpr float NEGV   = -1e9f;
constexpr float LN_EPS = 1e-5f;
constexpr int G  = 256;   // workgroups (<=256 CUs -> co-resident)
constexpr int BT = 512;   // 8 waves

typedef __attribute__((ext_vector_type(8))) short bf16x8;
typedef __attribute__((ext_vector_type(4))) float f32x4;
typedef unsigned long long u64;
typedef unsigned short u16;

__device__ __forceinline__ float sigmoidf_(float x) { return 1.f / (1.f + expf(-x)); }
__device__ __forceinline__ u16 f2bf(float x) {
  unsigned u = __float_as_uint(x);
  return (u16)((u + 0x7fffu + ((u >> 16) & 1u)) >> 16);
}
__device__ __forceinline__ float bf2f(u16 h) { return __uint_as_float((unsigned)h << 16); }
__device__ __forceinline__ unsigned mono(float f) {
  unsigned u = __float_as_uint(f);
  return (u & 0x80000000u) ? ~u : (u | 0x80000000u);
}
__device__ __forceinline__ u64 shfl_xor_u64(u64 x, int off) {
  unsigned lo = (unsigned)x, hi = (unsigned)(x >> 32);
  lo = __shfl_xor(lo, off, 64);
  hi = __shfl_xor(hi, off, 64);
  return ((u64)hi << 32) | lo;
}

// Contention-free grid barrier: per-block flag lines (parallel release stores),
// block 0 gathers with 255 threads, releases one `go` line everyone polls.
// Monotone epochs; flags/go zeroed by k_zero each launch.
__device__ __forceinline__ void gridbar(unsigned* flags, unsigned* go, unsigned epoch) {
  __syncthreads();
  if (blockIdx.x == 0) {
    int i = threadIdx.x;
    if (i >= 1 && i < G) {
      while (__hip_atomic_load(&flags[i * 32], __ATOMIC_ACQUIRE, __HIP_MEMORY_SCOPE_AGENT) < epoch)
        __builtin_amdgcn_s_sleep(2);
    }
    __syncthreads();
    if (i == 0)
      __hip_atomic_store(go, epoch, __ATOMIC_RELEASE, __HIP_MEMORY_SCOPE_AGENT);
  } else {
    if (threadIdx.x == 0) {
      __hip_atomic_store(&flags[blockIdx.x * 32], epoch, __ATOMIC_RELEASE, __HIP_MEMORY_SCOPE_AGENT);
      while (__hip_atomic_load(go, __ATOMIC_ACQUIRE, __HIP_MEMORY_SCOPE_AGENT) < epoch)
        __builtin_amdgcn_s_sleep(2);
    }
    __syncthreads();
  }
}

__global__ __launch_bounds__(1024) void k_zero(unsigned* flags, int n) {
  for (int i = blockIdx.x * 1024 + threadIdx.x; i < n; i += gridDim.x * 1024) flags[i] = 0u;
}

// ---------------------------------------------------------------------------
__global__ __launch_bounds__(BT, 2) void k_all(
    const float* __restrict__ enc, const int* __restrict__ lens,
    const float* __restrict__ emb,
    const float* __restrict__ w_ih, const float* __restrict__ w_hh,
    const float* __restrict__ b_ih, const float* __restrict__ b_hh,
    const float* __restrict__ attn_w, const float* __restrict__ concat_w,
    const float* __restrict__ gamma, const float* __restrict__ beta,
    const float* __restrict__ proj_w, float* __restrict__ out,
    unsigned* flags, unsigned* go,
    float* h32, float* c32, float* awT, float* cwT, float* biasc,
    u64* amax, u16* hh, u16* hl, u16* th, u16* tl,
    u16* wch, u16* wcl, u16* ebh, u16* ebl, u16* pwh, u16* pwl) {
  __shared__ float eL[64 * Hn];        // 80 KB enc chunk
  __shared__ float hs[Hn], ahs[Hn], cts[Hn];
  __shared__ float sc[64];
  __shared__ float rmS, rsS, rfS, rmu, rvar;

  const int bid = blockIdx.x, tid = threadIdx.x;
  const int wv = tid >> 6, lane = tid & 63;
  const int gid = bid * BT + tid;
  const int NT = G * BT;
  unsigned nb = 0;

  // ================= phase 0: one-time prep =================
  for (int i = gid; i < Vn * Hn / 4; i += NT) {
    float4 v = ((const float4*)proj_w)[i];
    u16 h0_ = f2bf(v.x), h1_ = f2bf(v.y), h2_ = f2bf(v.z), h3_ = f2bf(v.w);
    ((ushort4*)pwh)[i] = make_ushort4(h0_, h1_, h2_, h3_);
    ((ushort4*)pwl)[i] = make_ushort4(f2bf(v.x - bf2f(h0_)), f2bf(v.y - bf2f(h1_)),
                                      f2bf(v.z - bf2f(h2_)), f2bf(v.w - bf2f(h3_)));
  }
  for (int i = gid; i < Vn * En / 4; i += NT) {
    float4 v = ((const float4*)emb)[i];
    u16 h0_ = f2bf(v.x), h1_ = f2bf(v.y), h2_ = f2bf(v.z), h3_ = f2bf(v.w);
    ((ushort4*)ebh)[i] = make_ushort4(h0_, h1_, h2_, h3_);
    ((ushort4*)ebl)[i] = make_ushort4(f2bf(v.x - bf2f(h0_)), f2bf(v.y - bf2f(h1_)),
                                      f2bf(v.z - bf2f(h2_)), f2bf(v.w - bf2f(h3_)));
  }
  for (int i = gid; i < 4 * Hn * 112; i += NT) {  // w_cat [1280][448] split
    int r = i / 112, k = (i % 112) * 4;
    const float* src = (k < En) ? (w_ih + (size_t)r * En + k)
                                : (w_hh + (size_t)r * Hn + (k - En));
    float4 v = *(const float4*)src;
    size_t o = (size_t)r * 448 + k;
    u16 h0_ = f2bf(v.x), h1_ = f2bf(v.y), h2_ = f2bf(v.z), h3_ = f2bf(v.w);
    *(ushort4*)(wch + o) = make_ushort4(h0_, h1_, h2_, h3_);
    *(ushort4*)(wcl + o) = make_ushort4(f2bf(v.x - bf2f(h0_)), f2bf(v.y - bf2f(h1_)),
                                        f2bf(v.z - bf2f(h2_)), f2bf(v.w - bf2f(h3_)));
  }
  for (int i = gid; i < Hn * Hn; i += NT) {       // awT[k][j] = attn_w[j][k]
    int k = i / Hn, j = i % Hn;
    awT[i] = attn_w[(size_t)j * Hn + k];
  }
  for (int i = gid; i < 2 * Hn * Hn; i += NT) {   // cwT[k][j] = concat_w[j][k]
    int k = i / Hn, j = i % Hn;
    cwT[i] = concat_w[(size_t)j * (2 * Hn) + k];
  }
  for (int i = gid; i < 4 * Hn; i += NT) biasc[i] = b_ih[i] + b_hh[i];
  for (int i = gid; i < Tn * Bn; i += NT) amax[i] = 0ull;
  {
    if (tid < Hn) {
      const float* p = enc + (size_t)bid * Ln * Hn + tid;
      float s = 0.f;
#pragma unroll 4
      for (int l = 0; l < Ln; ++l) s += p[(size_t)l * Hn];
      float hv = s / (float)lens[bid];
      size_t o = (size_t)bid * Hn + tid;
      h32[o] = hv; c32[o] = hv;
      u16 hb = f2bf(hv);
      hh[o] = hb; hl[o] = f2bf(hv - bf2f(hb));
    }
  }
  nb += 1; gridbar(flags, go, nb);

  // ================= decode steps =================
  for (int t = 0; t < Tn; ++t) {
    const int hin = t & 1, hout = hin ^ 1;
    const size_t HB = (size_t)Bn * Hn;

    // ---- phase A: gates GEMM (split-bf16 MFMA) + LSTM cell ----
    // 20 blocks x 8 waves; wave tile = 32 b-rows x (4 gates x 16 h-cols)
    if (bid < 20) {
      int j0 = bid * 16;
      int b0 = wv * 32;
      int lr = lane & 15, hi4 = lane >> 4, kg = hi4 * 8;
      int tkr[2];
#pragma unroll
      for (int mt = 0; mt < 2; ++mt) {
        int r = b0 + mt * 16 + lr;
        tkr[mt] = (t == 0) ? 1 : (int)(~(unsigned)amax[(size_t)(t - 1) * Bn + r]);
      }
      f32x4 acc[2][4];
#pragma unroll
      for (int i = 0; i < 2; ++i)
#pragma unroll
        for (int j = 0; j < 4; ++j) acc[i][j] = (f32x4){0.f, 0.f, 0.f, 0.f};
      const u16* hhi = hh + hin * HB;
      const u16* hli = hl + hin * HB;
      for (int k0 = 0; k0 < 448; k0 += 32) {
        bf16x8 af[2][2], bw[4][2];
#pragma unroll
        for (int mt = 0; mt < 2; ++mt) {
          int r = b0 + mt * 16 + lr;
          if (k0 < En) {
            size_t o = (size_t)tkr[mt] * En + k0 + kg;
            af[mt][0] = *(const bf16x8*)(ebh + o);
            af[mt][1] = *(const bf16x8*)(ebl + o);
          } else {
            size_t o = (size_t)r * Hn + (k0 - En) + kg;
            af[mt][0] = *(const bf16x8*)(hhi + o);
            af[mt][1] = *(const bf16x8*)(hli + o);
          }
        }
#pragma unroll
        for (int g = 0; g < 4; ++g) {
          size_t o = (size_t)(g * Hn + j0 + lr) * 448 + k0 + kg;
          bw[g][0] = *(const bf16x8*)(wch + o);
          bw[g][1] = *(const bf16x8*)(wcl + o);
        }
#pragma unroll
        for (int mt = 0; mt < 2; ++mt)
#pragma unroll
          for (int g = 0; g < 4; ++g) {
            acc[mt][g] = __builtin_amdgcn_mfma_f32_16x16x32_bf16(af[mt][0], bw[g][0], acc[mt][g], 0, 0, 0);
            acc[mt][g] = __builtin_amdgcn_mfma_f32_16x16x32_bf16(af[mt][0], bw[g][1], acc[mt][g], 0, 0, 0);
            acc[mt][g] = __builtin_amdgcn_mfma_f32_16x16x32_bf16(af[mt][1], bw[g][0], acc[mt][g], 0, 0, 0);
          }
      }
      int jc = j0 + lr;
      const float* c_i = c32 + hin * HB;
      float* c_o = c32 + hout * HB;
      float* h_o = h32 + hout * HB;
      u16* hho = hh + hout * HB;
      u16* hlo = hl + hout * HB;
#pragma unroll
      for (int mt = 0; mt < 2; ++mt)
#pragma unroll
        for (int j = 0; j < 4; ++j) {
          int b = b0 + mt * 16 + hi4 * 4 + j;
          float iv = acc[mt][0][j] + biasc[jc];
          float fv = acc[mt][1][j] + biasc[Hn + jc];
          float gv = acc[mt][2][j] + biasc[2 * Hn + jc];
          float ov = acc[mt][3][j] + biasc[3 * Hn + jc];
          float co = c_i[(size_t)b * Hn + jc];
          float cn = sigmoidf_(fv) * co + sigmoidf_(iv) * tanhf(gv);
          float hn = sigmoidf_(ov) * tanhf(cn);
          size_t o = (size_t)b * Hn + jc;
          c_o[o] = cn; h_o[o] = hn;
          u16 hb = f2bf(hn);
          hho[o] = hb; hlo[o] = f2bf(hn - bf2f(hb));
        }
    }
    nb += 1; gridbar(flags, go, nb);

    // ---- phase B: attention (online softmax, single enc pass) + cat + LN ----
    {
      int b = bid;
      const float* hsrc = h32 + hout * HB + (size_t)b * Hn;
      if (tid < Hn) hs[tid] = hsrc[tid];
      __syncthreads();
      if (tid < Hn) {
        float s = 0.f;
#pragma unroll 8
        for (int k = 0; k < Hn; ++k) s += awT[(size_t)k * Hn + tid] * hs[k];
        ahs[tid] = s;
      }
      if (tid == 0) { rmS = -3.402823466e38f; rsS = 0.f; }
      __syncthreads();

      int len = lens[b];
      float ctxacc = 0.f;
      const float* encB = enc + (size_t)b * Ln * Hn;
      for (int c = 0; c < 3; ++c) {
        // stage 64 x 320 chunk into LDS
        const float4* src = (const float4*)(encB + (size_t)c * 64 * Hn);
#pragma unroll
        for (int i = 0; i < 10; ++i) ((float4*)eL)[tid + i * BT] = src[tid + i * BT];
        __syncthreads();
        // scores for 8 rows per wave
#pragma unroll
        for (int r = 0; r < 8; ++r) {
          int l = wv * 8 + r;
          float s = 0.f;
#pragma unroll
          for (int c5 = 0; c5 < 5; ++c5)
            s += eL[l * Hn + lane + 64 * c5] * ahs[lane + 64 * c5];
#pragma unroll
          for (int off = 32; off > 0; off >>= 1) s += __shfl_xor(s, off, 64);
          if (lane == 0) sc[l] = s + ((c * 64 + l < len) ? 0.f : NEGV);
        }
        __syncthreads();
        // online softmax update (wave 0)
        if (wv == 0) {
          float v = sc[lane];
          float m = v;
#pragma unroll
          for (int off = 32; off > 0; off >>= 1) m = fmaxf(m, __shfl_xor(m, off, 64));
          float oldm = rmS;
          float newm = fmaxf(oldm, m);
          float p = expf(v - newm);
          sc[lane] = p;
          float s = p;
#pragma unroll
          for (int off = 32; off > 0; off >>= 1) s += __shfl_xor(s, off, 64);
          if (lane == 0) {
            float f = expf(oldm - newm);
            rfS = f;
            rsS = rsS * f + s;
            rmS = newm;
          }
        }
        __syncthreads();
        // ctx accumulate from LDS
        if (tid < Hn) {
          float f = rfS;
          float a = 0.f;
#pragma unroll 8
          for (int l = 0; l < 64; ++l) a += sc[l] * eL[l * Hn + tid];
          ctxacc = ctxacc * f + a;
        }
        __syncthreads();
      }
      if (tid < Hn) cts[tid] = ctxacc / rsS;
      __syncthreads();

      // cat matvec + LN + tanh
      float catv = 0.f;
      if (tid < Hn) {
        float s = 0.f;
#pragma unroll 8
        for (int k = 0; k < Hn; ++k) s += cwT[(size_t)k * Hn + tid] * hs[k];
#pragma unroll 8
        for (int k = 0; k < Hn; ++k) s += cwT[(size_t)(Hn + k) * Hn + tid] * cts[k];
        catv = s;
        ahs[tid] = s;
      }
      __syncthreads();
      if (tid < 64) {
        float s1 = 0.f, s2 = 0.f;
        for (int i = tid; i < Hn; i += 64) { float v = ahs[i]; s1 += v; s2 += v * v; }
#pragma unroll
        for (int off = 32; off > 0; off >>= 1) {
          s1 += __shfl_xor(s1, off, 64);
          s2 += __shfl_xor(s2, off, 64);
        }
        if (tid == 0) {
          float mu = s1 * (1.f / 320.f);
          rmu = mu;
          rvar = s2 * (1.f / 320.f) - mu * mu;
        }
      }
      __syncthreads();
      if (tid < Hn) {
        float rstd = 1.f / sqrtf(rvar + LN_EPS);
        float y = (catv - rmu) * rstd * gamma[tid] + beta[tid];
        float tv = tanhf(y);
        u16 tb = f2bf(tv);
        size_t o = (size_t)b * Hn + tid;
        th[o] = tb;
        tl[o] = f2bf(tv - bf2f(tb));
      }
    }
    nb += 1; gridbar(flags, go, nb);

    // ---- phase C: projection (split-bf16 MFMA) + fused argmax ----
    // XCD-contiguous tiles: xcd = bid&7 owns tiles [xcd*211, xcd*211+210]
    {
      int xcd = bid & 7, slot = bid >> 3;
      int idx = slot * 8 + wv;
      if (idx < 211) {
        int tile = xcd * 211 + idx;
        int mb = tile & 3, vb = tile >> 2;
        int b0 = mb * 64, v0 = vb * 64;
        int lr = lane & 15, hi4 = lane >> 4, kg = hi4 * 8;
        f32x4 acc[4][4];
#pragma unroll
        for (int i = 0; i < 4; ++i)
#pragma unroll
          for (int j = 0; j < 4; ++j) acc[i][j] = (f32x4){0.f, 0.f, 0.f, 0.f};
        const bf16x8 zf = {0, 0, 0, 0, 0, 0, 0, 0};
        for (int k0 = 0; k0 < Hn; k0 += 32) {
          bf16x8 af[4][2], bw[4][2];
#pragma unroll
          for (int mt = 0; mt < 4; ++mt) {
            size_t o = (size_t)(b0 + mt * 16 + lr) * Hn + k0 + kg;
            af[mt][0] = *(const bf16x8*)(th + o);
            af[mt][1] = *(const bf16x8*)(tl + o);
          }
#pragma unroll
          for (int nt = 0; nt < 4; ++nt) {
            int v = v0 + nt * 16 + lr;
            if (v < Vn) {
              size_t o = (size_t)v * Hn + k0 + kg;
              bw[nt][0] = *(const bf16x8*)(pwh + o);
              bw[nt][1] = *(const bf16x8*)(pwl + o);
            } else {
              bw[nt][0] = zf; bw[nt][1] = zf;
            }
          }
#pragma unroll
          for (int mt = 0; mt < 4; ++mt)
#pragma unroll
            for (int nt = 0; nt < 4; ++nt) {
              acc[mt][nt] = __builtin_amdgcn_mfma_f32_16x16x32_bf16(af[mt][0], bw[nt][0], acc[mt][nt], 0, 0, 0);
              acc[mt][nt] = __builtin_amdgcn_mfma_f32_16x16x32_bf16(af[mt][0], bw[nt][1], acc[mt][nt], 0, 0, 0);
              acc[mt][nt] = __builtin_amdgcn_mfma_f32_16x16x32_bf16(af[mt][1], bw[nt][0], acc[mt][nt], 0, 0, 0);
            }
        }
        float* ot = out + (size_t)t * Bn * Vn;
#pragma unroll
        for (int mt = 0; mt < 4; ++mt)
#pragma unroll
          for (int nt = 0; nt < 4; ++nt) {
            int v = v0 + nt * 16 + lr;
            if (v < Vn) {
#pragma unroll
              for (int j = 0; j < 4; ++j)
                ot[(size_t)(b0 + mt * 16 + hi4 * 4 + j) * Vn + v] = acc[mt][nt][j];
            }
          }
        // argmax: key = (mono(val)<<32) | ~idx ; max key == first max
#pragma unroll
        for (int mt = 0; mt < 4; ++mt)
#pragma unroll
          for (int j = 0; j < 4; ++j) {
            u64 k = 0ull;
#pragma unroll
            for (int nt = 0; nt < 4; ++nt) {
              int v = v0 + nt * 16 + lr;
              if (v < Vn) {
                u64 kk = ((u64)mono(acc[mt][nt][j]) << 32) | (u64)(unsigned)(~v);
                if (kk > k) k = kk;
              }
            }
#pragma unroll
            for (int off = 1; off < 16; off <<= 1) {
              u64 o = shfl_xor_u64(k, off);
              if (o > k) k = o;
            }
            if (lr == 0) {
              int b = b0 + mt * 16 + hi4 * 4 + j;
              atomicMax(&amax[(size_t)t * Bn + b], k);
            }
          }
      }
    }
    if (t != Tn - 1) { nb += 1; gridbar(flags, go, nb); }
  }
}

// ---------------------------------------------------------------------------
extern "C" void kernel_launch(void* const* d_in, const int* in_sizes, int n_in,
                              void* d_out, int out_size, void* d_ws, size_t ws_size,
                              hipStream_t stream) {
  const float* enc      = (const float*)d_in[0];
  const int*   lens     = (const int*)d_in[1];
  const float* emb      = (const float*)d_in[2];
  const float* w_ih     = (const float*)d_in[3];
  const float* w_hh     = (const float*)d_in[4];
  const float* b_ih     = (const float*)d_in[5];
  const float* b_hh     = (const float*)d_in[6];
  const float* attn_w   = (const float*)d_in[7];
  const float* concat_w = (const float*)d_in[8];
  const float* gamma    = (const float*)d_in[9];
  const float* beta     = (const float*)d_in[10];
  const float* proj_w   = (const float*)d_in[11];
  float* out = (float*)d_out;

  char* p = (char*)d_ws;
  auto alloc = [&](size_t bytes, size_t align) -> char* {
    uintptr_t a = ((uintptr_t)p + align - 1) & ~(uintptr_t)(align - 1);
    char* r = (char*)a;
    p = r + bytes;
    return r;
  };
  unsigned* flags = (unsigned*)alloc(257 * 32 * 4, 128);  // 256 flag lines + go line
  unsigned* go = flags + 256 * 32;
  u64* amax  = (u64*)alloc((size_t)Tn * Bn * 8, 8);
  float* h32 = (float*)alloc((size_t)2 * Bn * Hn * 4, 4);
  float* c32 = (float*)alloc((size_t)2 * Bn * Hn * 4, 4);
  float* awT = (float*)alloc((size_t)Hn * Hn * 4, 4);
  float* cwT = (float*)alloc((size_t)2 * Hn * Hn * 4, 4);
  float* biasc = (float*)alloc((size_t)4 * Hn * 4, 4);
  u16* hh  = (u16*)alloc((size_t)2 * Bn * Hn * 2, 8);
  u16* hl  = (u16*)alloc((size_t)2 * Bn * Hn * 2, 8);
  u16* th  = (u16*)alloc((size_t)Bn * Hn * 2, 8);
  u16* tl  = (u16*)alloc((size_t)Bn * Hn * 2, 8);
  u16* wch = (u16*)alloc((size_t)4 * Hn * 448 * 2, 8);
  u16* wcl = (u16*)alloc((size_t)4 * Hn * 448 * 2, 8);
  u16* ebh = (u16*)alloc((size_t)Vn * En * 2, 8);
  u16* ebl = (u16*)alloc((size_t)Vn * En * 2, 8);
  u16* pwh = (u16*)alloc((size_t)Vn * Hn * 2, 8);
  u16* pwl = (u16*)alloc((size_t)Vn * Hn * 2, 8);

  k_zero<<<8, 1024, 0, stream>>>(flags, 257 * 32);
  k_all<<<G, BT, 0, stream>>>(enc, lens, emb, w_ih, w_hh, b_ih, b_hh,
                              attn_w, concat_w, gamma, beta, proj_w, out,
                              flags, go, h32, c32, awT, cwT, biasc,
                              amax, hh, hl, th, tl,
                              wch, wcl, ebh, ebl, pwh, pwl);
}

// Round 6
// 1566.869 us; speedup vs baseline: 2.3429x; 2.3429x over previous
//
#include <hip/hip_runtime.h>

// PathDecoder: B=256, L=192, H=320, E=128, V=27000, T=8
constexpr int Bn = 256;
constexpr int Ln = 192;
constexpr int Hn = 320;
constexpr int En = 128;
constexpr int Vn = 27000;
constexpr int Tn = 8;
constexpr float NEGV   = -1e9f;
constexpr float LN_EPS = 1e-5f;
constexpr int G  = 256;   // workgroups (<=256 CUs -> co-resident)
constexpr int BT = 512;   // 8 waves

typedef __attribute__((ext_vector_type(8))) short bf16x8;
typedef __attribute__((ext_vector_type(4))) float f32x4;
typedef unsigned long long u64;
typedef unsigned short u16;

__device__ __forceinline__ float sigmoidf_(float x) { return 1.f / (1.f + expf(-x)); }
__device__ __forceinline__ u16 f2bf(float x) {
  unsigned u = __float_as_uint(x);
  return (u16)((u + 0x7fffu + ((u >> 16) & 1u)) >> 16);
}
__device__ __forceinline__ float bf2f(u16 h) { return __uint_as_float((unsigned)h << 16); }
__device__ __forceinline__ unsigned mono(float f) {
  unsigned u = __float_as_uint(f);
  return (u & 0x80000000u) ? ~u : (u | 0x80000000u);
}
__device__ __forceinline__ u64 shfl_xor_u64(u64 x, int off) {
  unsigned lo = (unsigned)x, hi = (unsigned)(x >> 32);
  lo = __shfl_xor(lo, off, 64);
  hi = __shfl_xor(hi, off, 64);
  return ((u64)hi << 32) | lo;
}

// Grid barrier with RELAXED polling (no per-iteration cache invalidate).
// Arrivals: one RELEASE store per block (parallel L2 writebacks).
// Block 0 gathers flags with relaxed loads, then ONE acquire, then releases go.
// Other blocks poll go relaxed, then ONE acquire load (single L1/L2 inv).
__device__ __forceinline__ void gridbar(unsigned* flags, unsigned* go, unsigned epoch) {
  __syncthreads();
  if (blockIdx.x == 0) {
    int i = threadIdx.x;
    if (i >= 1 && i < G) {
      while (__hip_atomic_load(&flags[i * 32], __ATOMIC_RELAXED, __HIP_MEMORY_SCOPE_AGENT) < epoch)
        __builtin_amdgcn_s_sleep(8);
    }
    __syncthreads();
    if (i == 0) {
      unsigned g = __hip_atomic_load(&flags[32], __ATOMIC_ACQUIRE, __HIP_MEMORY_SCOPE_AGENT);
      asm volatile("" :: "v"(g));
      __hip_atomic_store(go, epoch, __ATOMIC_RELEASE, __HIP_MEMORY_SCOPE_AGENT);
    }
    __syncthreads();
  } else {
    if (threadIdx.x == 0) {
      __hip_atomic_store(&flags[blockIdx.x * 32], epoch, __ATOMIC_RELEASE, __HIP_MEMORY_SCOPE_AGENT);
      while (__hip_atomic_load(go, __ATOMIC_RELAXED, __HIP_MEMORY_SCOPE_AGENT) < epoch)
        __builtin_amdgcn_s_sleep(8);
      unsigned g = __hip_atomic_load(go, __ATOMIC_ACQUIRE, __HIP_MEMORY_SCOPE_AGENT);
      asm volatile("" :: "v"(g));
    }
    __syncthreads();
  }
}

__global__ __launch_bounds__(1024) void k_zero(unsigned* flags, int n) {
  for (int i = blockIdx.x * 1024 + threadIdx.x; i < n; i += gridDim.x * 1024) flags[i] = 0u;
}

// ---------------------------------------------------------------------------
__global__ __launch_bounds__(BT, 2) void k_all(
    const float* __restrict__ enc, const int* __restrict__ lens,
    const float* __restrict__ emb,
    const float* __restrict__ w_ih, const float* __restrict__ w_hh,
    const float* __restrict__ b_ih, const float* __restrict__ b_hh,
    const float* __restrict__ attn_w, const float* __restrict__ concat_w,
    const float* __restrict__ gamma, const float* __restrict__ beta,
    const float* __restrict__ proj_w, float* __restrict__ out,
    unsigned* flags, unsigned* go,
    float* h32, float* c32, float* awT, float* cwT, float* biasc,
    u64* amax, u16* hh, u16* hl, u16* th, u16* tl,
    u16* wch, u16* wcl, u16* ebh, u16* ebl, u16* pwh, u16* pwl) {
  __shared__ float eL[64 * Hn];        // 80 KB enc chunk
  __shared__ float hs[Hn], ahs[Hn], cts[Hn];
  __shared__ float sc[64];
  __shared__ float rmS, rsS, rfS, rmu, rvar;

  const int bid = blockIdx.x, tid = threadIdx.x;
  const int wv = tid >> 6, lane = tid & 63;
  const int gid = bid * BT + tid;
  const int NT = G * BT;
  unsigned nb = 0;

  // ================= phase 0: one-time prep =================
  for (int i = gid; i < Vn * Hn / 4; i += NT) {
    float4 v = ((const float4*)proj_w)[i];
    u16 h0_ = f2bf(v.x), h1_ = f2bf(v.y), h2_ = f2bf(v.z), h3_ = f2bf(v.w);
    ((ushort4*)pwh)[i] = make_ushort4(h0_, h1_, h2_, h3_);
    ((ushort4*)pwl)[i] = make_ushort4(f2bf(v.x - bf2f(h0_)), f2bf(v.y - bf2f(h1_)),
                                      f2bf(v.z - bf2f(h2_)), f2bf(v.w - bf2f(h3_)));
  }
  for (int i = gid; i < Vn * En / 4; i += NT) {
    float4 v = ((const float4*)emb)[i];
    u16 h0_ = f2bf(v.x), h1_ = f2bf(v.y), h2_ = f2bf(v.z), h3_ = f2bf(v.w);
    ((ushort4*)ebh)[i] = make_ushort4(h0_, h1_, h2_, h3_);
    ((ushort4*)ebl)[i] = make_ushort4(f2bf(v.x - bf2f(h0_)), f2bf(v.y - bf2f(h1_)),
                                      f2bf(v.z - bf2f(h2_)), f2bf(v.w - bf2f(h3_)));
  }
  for (int i = gid; i < 4 * Hn * 112; i += NT) {  // w_cat [1280][448] split
    int r = i / 112, k = (i % 112) * 4;
    const float* src = (k < En) ? (w_ih + (size_t)r * En + k)
                                : (w_hh + (size_t)r * Hn + (k - En));
    float4 v = *(const float4*)src;
    size_t o = (size_t)r * 448 + k;
    u16 h0_ = f2bf(v.x), h1_ = f2bf(v.y), h2_ = f2bf(v.z), h3_ = f2bf(v.w);
    *(ushort4*)(wch + o) = make_ushort4(h0_, h1_, h2_, h3_);
    *(ushort4*)(wcl + o) = make_ushort4(f2bf(v.x - bf2f(h0_)), f2bf(v.y - bf2f(h1_)),
                                        f2bf(v.z - bf2f(h2_)), f2bf(v.w - bf2f(h3_)));
  }
  for (int i = gid; i < Hn * Hn; i += NT) {       // awT[k][j] = attn_w[j][k]
    int k = i / Hn, j = i % Hn;
    awT[i] = attn_w[(size_t)j * Hn + k];
  }
  for (int i = gid; i < 2 * Hn * Hn; i += NT) {   // cwT[k][j] = concat_w[j][k]
    int k = i / Hn, j = i % Hn;
    cwT[i] = concat_w[(size_t)j * (2 * Hn) + k];
  }
  for (int i = gid; i < 4 * Hn; i += NT) biasc[i] = b_ih[i] + b_hh[i];
  for (int i = gid; i < Tn * Bn; i += NT) amax[i] = 0ull;
  {
    if (tid < Hn) {
      const float* p = enc + (size_t)bid * Ln * Hn + tid;
      float s = 0.f;
#pragma unroll 4
      for (int l = 0; l < Ln; ++l) s += p[(size_t)l * Hn];
      float hv = s / (float)lens[bid];
      size_t o = (size_t)bid * Hn + tid;
      h32[o] = hv; c32[o] = hv;
      u16 hb = f2bf(hv);
      hh[o] = hb; hl[o] = f2bf(hv - bf2f(hb));
    }
  }
  nb += 1; gridbar(flags, go, nb);

  // ================= decode steps =================
  for (int t = 0; t < Tn; ++t) {
    const int hin = t & 1, hout = hin ^ 1;
    const size_t HB = (size_t)Bn * Hn;

    // ---- phase A: gates GEMM (split-bf16 MFMA) + LSTM cell ----
    // 20 blocks x 8 waves; wave tile = 32 b-rows x (4 gates x 16 h-cols)
    if (bid < 20) {
      int j0 = bid * 16;
      int b0 = wv * 32;
      int lr = lane & 15, hi4 = lane >> 4, kg = hi4 * 8;
      int tkr[2];
#pragma unroll
      for (int mt = 0; mt < 2; ++mt) {
        int r = b0 + mt * 16 + lr;
        tkr[mt] = (t == 0) ? 1 : (int)(~(unsigned)amax[(size_t)(t - 1) * Bn + r]);
      }
      f32x4 acc[2][4];
#pragma unroll
      for (int i = 0; i < 2; ++i)
#pragma unroll
        for (int j = 0; j < 4; ++j) acc[i][j] = (f32x4){0.f, 0.f, 0.f, 0.f};
      const u16* hhi = hh + hin * HB;
      const u16* hli = hl + hin * HB;
      for (int k0 = 0; k0 < 448; k0 += 32) {
        bf16x8 af[2][2], bw[4][2];
#pragma unroll
        for (int mt = 0; mt < 2; ++mt) {
          int r = b0 + mt * 16 + lr;
          if (k0 < En) {
            size_t o = (size_t)tkr[mt] * En + k0 + kg;
            af[mt][0] = *(const bf16x8*)(ebh + o);
            af[mt][1] = *(const bf16x8*)(ebl + o);
          } else {
            size_t o = (size_t)r * Hn + (k0 - En) + kg;
            af[mt][0] = *(const bf16x8*)(hhi + o);
            af[mt][1] = *(const bf16x8*)(hli + o);
          }
        }
#pragma unroll
        for (int g = 0; g < 4; ++g) {
          size_t o = (size_t)(g * Hn + j0 + lr) * 448 + k0 + kg;
          bw[g][0] = *(const bf16x8*)(wch + o);
          bw[g][1] = *(const bf16x8*)(wcl + o);
        }
#pragma unroll
        for (int mt = 0; mt < 2; ++mt)
#pragma unroll
          for (int g = 0; g < 4; ++g) {
            acc[mt][g] = __builtin_amdgcn_mfma_f32_16x16x32_bf16(af[mt][0], bw[g][0], acc[mt][g], 0, 0, 0);
            acc[mt][g] = __builtin_amdgcn_mfma_f32_16x16x32_bf16(af[mt][0], bw[g][1], acc[mt][g], 0, 0, 0);
            acc[mt][g] = __builtin_amdgcn_mfma_f32_16x16x32_bf16(af[mt][1], bw[g][0], acc[mt][g], 0, 0, 0);
          }
      }
      int jc = j0 + lr;
      const float* c_i = c32 + hin * HB;
      float* c_o = c32 + hout * HB;
      float* h_o = h32 + hout * HB;
      u16* hho = hh + hout * HB;
      u16* hlo = hl + hout * HB;
#pragma unroll
      for (int mt = 0; mt < 2; ++mt)
#pragma unroll
        for (int j = 0; j < 4; ++j) {
          int b = b0 + mt * 16 + hi4 * 4 + j;
          float iv = acc[mt][0][j] + biasc[jc];
          float fv = acc[mt][1][j] + biasc[Hn + jc];
          float gv = acc[mt][2][j] + biasc[2 * Hn + jc];
          float ov = acc[mt][3][j] + biasc[3 * Hn + jc];
          float co = c_i[(size_t)b * Hn + jc];
          float cn = sigmoidf_(fv) * co + sigmoidf_(iv) * tanhf(gv);
          float hn = sigmoidf_(ov) * tanhf(cn);
          size_t o = (size_t)b * Hn + jc;
          c_o[o] = cn; h_o[o] = hn;
          u16 hb = f2bf(hn);
          hho[o] = hb; hlo[o] = f2bf(hn - bf2f(hb));
        }
    }
    nb += 1; gridbar(flags, go, nb);

    // ---- phase B: attention (online softmax, single enc pass) + cat + LN ----
    {
      int b = bid;
      const float* hsrc = h32 + hout * HB + (size_t)b * Hn;
      if (tid < Hn) hs[tid] = hsrc[tid];
      __syncthreads();
      if (tid < Hn) {
        float s = 0.f;
#pragma unroll 8
        for (int k = 0; k < Hn; ++k) s += awT[(size_t)k * Hn + tid] * hs[k];
        ahs[tid] = s;
      }
      if (tid == 0) { rmS = -3.402823466e38f; rsS = 0.f; }
      __syncthreads();

      int len = lens[b];
      float ctxacc = 0.f;
      const float* encB = enc + (size_t)b * Ln * Hn;
      for (int c = 0; c < 3; ++c) {
        const float4* src = (const float4*)(encB + (size_t)c * 64 * Hn);
#pragma unroll
        for (int i = 0; i < 10; ++i) ((float4*)eL)[tid + i * BT] = src[tid + i * BT];
        __syncthreads();
#pragma unroll
        for (int r = 0; r < 8; ++r) {
          int l = wv * 8 + r;
          float s = 0.f;
#pragma unroll
          for (int c5 = 0; c5 < 5; ++c5)
            s += eL[l * Hn + lane + 64 * c5] * ahs[lane + 64 * c5];
#pragma unroll
          for (int off = 32; off > 0; off >>= 1) s += __shfl_xor(s, off, 64);
          if (lane == 0) sc[l] = s + ((c * 64 + l < len) ? 0.f : NEGV);
        }
        __syncthreads();
        if (wv == 0) {
          float v = sc[lane];
          float m = v;
#pragma unroll
          for (int off = 32; off > 0; off >>= 1) m = fmaxf(m, __shfl_xor(m, off, 64));
          float oldm = rmS;
          float newm = fmaxf(oldm, m);
          float p = expf(v - newm);
          sc[lane] = p;
          float s = p;
#pragma unroll
          for (int off = 32; off > 0; off >>= 1) s += __shfl_xor(s, off, 64);
          if (lane == 0) {
            float f = expf(oldm - newm);
            rfS = f;
            rsS = rsS * f + s;
            rmS = newm;
          }
        }
        __syncthreads();
        if (tid < Hn) {
          float f = rfS;
          float a = 0.f;
#pragma unroll 8
          for (int l = 0; l < 64; ++l) a += sc[l] * eL[l * Hn + tid];
          ctxacc = ctxacc * f + a;
        }
        __syncthreads();
      }
      if (tid < Hn) cts[tid] = ctxacc / rsS;
      __syncthreads();

      float catv = 0.f;
      if (tid < Hn) {
        float s = 0.f;
#pragma unroll 8
        for (int k = 0; k < Hn; ++k) s += cwT[(size_t)k * Hn + tid] * hs[k];
#pragma unroll 8
        for (int k = 0; k < Hn; ++k) s += cwT[(size_t)(Hn + k) * Hn + tid] * cts[k];
        catv = s;
        ahs[tid] = s;
      }
      __syncthreads();
      if (tid < 64) {
        float s1 = 0.f, s2 = 0.f;
        for (int i = tid; i < Hn; i += 64) { float v = ahs[i]; s1 += v; s2 += v * v; }
#pragma unroll
        for (int off = 32; off > 0; off >>= 1) {
          s1 += __shfl_xor(s1, off, 64);
          s2 += __shfl_xor(s2, off, 64);
        }
        if (tid == 0) {
          float mu = s1 * (1.f / 320.f);
          rmu = mu;
          rvar = s2 * (1.f / 320.f) - mu * mu;
        }
      }
      __syncthreads();
      if (tid < Hn) {
        float rstd = 1.f / sqrtf(rvar + LN_EPS);
        float y = (catv - rmu) * rstd * gamma[tid] + beta[tid];
        float tv = tanhf(y);
        u16 tb = f2bf(tv);
        size_t o = (size_t)b * Hn + tid;
        th[o] = tb;
        tl[o] = f2bf(tv - bf2f(tb));
      }
    }
    nb += 1; gridbar(flags, go, nb);

    // ---- phase C: projection (split-bf16 MFMA) + fused argmax ----
    // XCD-contiguous tiles: xcd = bid&7 owns tiles [xcd*211, xcd*211+210]
    {
      int xcd = bid & 7, slot = bid >> 3;
      int idx = slot * 8 + wv;
      if (idx < 211) {
        int tile = xcd * 211 + idx;
        int mb = tile & 3, vb = tile >> 2;
        int b0 = mb * 64, v0 = vb * 64;
        int lr = lane & 15, hi4 = lane >> 4, kg = hi4 * 8;
        f32x4 acc[4][4];
#pragma unroll
        for (int i = 0; i < 4; ++i)
#pragma unroll
          for (int j = 0; j < 4; ++j) acc[i][j] = (f32x4){0.f, 0.f, 0.f, 0.f};
        const bf16x8 zf = {0, 0, 0, 0, 0, 0, 0, 0};
        for (int k0 = 0; k0 < Hn; k0 += 32) {
          bf16x8 af[4][2], bw[4][2];
#pragma unroll
          for (int mt = 0; mt < 4; ++mt) {
            size_t o = (size_t)(b0 + mt * 16 + lr) * Hn + k0 + kg;
            af[mt][0] = *(const bf16x8*)(th + o);
            af[mt][1] = *(const bf16x8*)(tl + o);
          }
#pragma unroll
          for (int nt = 0; nt < 4; ++nt) {
            int v = v0 + nt * 16 + lr;
            if (v < Vn) {
              size_t o = (size_t)v * Hn + k0 + kg;
              bw[nt][0] = *(const bf16x8*)(pwh + o);
              bw[nt][1] = *(const bf16x8*)(pwl + o);
            } else {
              bw[nt][0] = zf; bw[nt][1] = zf;
            }
          }
#pragma unroll
          for (int mt = 0; mt < 4; ++mt)
#pragma unroll
            for (int nt = 0; nt < 4; ++nt) {
              acc[mt][nt] = __builtin_amdgcn_mfma_f32_16x16x32_bf16(af[mt][0], bw[nt][0], acc[mt][nt], 0, 0, 0);
              acc[mt][nt] = __builtin_amdgcn_mfma_f32_16x16x32_bf16(af[mt][0], bw[nt][1], acc[mt][nt], 0, 0, 0);
              acc[mt][nt] = __builtin_amdgcn_mfma_f32_16x16x32_bf16(af[mt][1], bw[nt][0], acc[mt][nt], 0, 0, 0);
            }
        }
        float* ot = out + (size_t)t * Bn * Vn;
        // non-temporal logits store: don't pollute IF$ (out is never re-read)
#pragma unroll
        for (int mt = 0; mt < 4; ++mt)
#pragma unroll
          for (int nt = 0; nt < 4; ++nt) {
            int v = v0 + nt * 16 + lr;
            if (v < Vn) {
#pragma unroll
              for (int j = 0; j < 4; ++j)
                __builtin_nontemporal_store(acc[mt][nt][j],
                    &ot[(size_t)(b0 + mt * 16 + hi4 * 4 + j) * Vn + v]);
            }
          }
        // argmax: key = (mono(val)<<32) | ~idx ; max key == first max
#pragma unroll
        for (int mt = 0; mt < 4; ++mt)
#pragma unroll
          for (int j = 0; j < 4; ++j) {
            u64 k = 0ull;
#pragma unroll
            for (int nt = 0; nt < 4; ++nt) {
              int v = v0 + nt * 16 + lr;
              if (v < Vn) {
                u64 kk = ((u64)mono(acc[mt][nt][j]) << 32) | (u64)(unsigned)(~v);
                if (kk > k) k = kk;
              }
            }
#pragma unroll
            for (int off = 1; off < 16; off <<= 1) {
              u64 o = shfl_xor_u64(k, off);
              if (o > k) k = o;
            }
            if (lr == 0) {
              int b = b0 + mt * 16 + hi4 * 4 + j;
              atomicMax(&amax[(size_t)t * Bn + b], k);
            }
          }
      }
    }
    if (t != Tn - 1) { nb += 1; gridbar(flags, go, nb); }
  }
}

// ---------------------------------------------------------------------------
extern "C" void kernel_launch(void* const* d_in, const int* in_sizes, int n_in,
                              void* d_out, int out_size, void* d_ws, size_t ws_size,
                              hipStream_t stream) {
  const float* enc      = (const float*)d_in[0];
  const int*   lens     = (const int*)d_in[1];
  const float* emb      = (const float*)d_in[2];
  const float* w_ih     = (const float*)d_in[3];
  const float* w_hh     = (const float*)d_in[4];
  const float* b_ih     = (const float*)d_in[5];
  const float* b_hh     = (const float*)d_in[6];
  const float* attn_w   = (const float*)d_in[7];
  const float* concat_w = (const float*)d_in[8];
  const float* gamma    = (const float*)d_in[9];
  const float* beta     = (const float*)d_in[10];
  const float* proj_w   = (const float*)d_in[11];
  float* out = (float*)d_out;

  char* p = (char*)d_ws;
  auto alloc = [&](size_t bytes, size_t align) -> char* {
    uintptr_t a = ((uintptr_t)p + align - 1) & ~(uintptr_t)(align - 1);
    char* r = (char*)a;
    p = r + bytes;
    return r;
  };
  unsigned* flags = (unsigned*)alloc(257 * 32 * 4, 128);  // 256 flag lines + go line
  unsigned* go = flags + 256 * 32;
  u64* amax  = (u64*)alloc((size_t)Tn * Bn * 8, 8);
  float* h32 = (float*)alloc((size_t)2 * Bn * Hn * 4, 4);
  float* c32 = (float*)alloc((size_t)2 * Bn * Hn * 4, 4);
  float* awT = (float*)alloc((size_t)Hn * Hn * 4, 4);
  float* cwT = (float*)alloc((size_t)2 * Hn * Hn * 4, 4);
  float* biasc = (float*)alloc((size_t)4 * Hn * 4, 4);
  u16* hh  = (u16*)alloc((size_t)2 * Bn * Hn * 2, 8);
  u16* hl  = (u16*)alloc((size_t)2 * Bn * Hn * 2, 8);
  u16* th  = (u16*)alloc((size_t)Bn * Hn * 2, 8);
  u16* tl  = (u16*)alloc((size_t)Bn * Hn * 2, 8);
  u16* wch = (u16*)alloc((size_t)4 * Hn * 448 * 2, 8);
  u16* wcl = (u16*)alloc((size_t)4 * Hn * 448 * 2, 8);
  u16* ebh = (u16*)alloc((size_t)Vn * En * 2, 8);
  u16* ebl = (u16*)alloc((size_t)Vn * En * 2, 8);
  u16* pwh = (u16*)alloc((size_t)Vn * Hn * 2, 8);
  u16* pwl = (u16*)alloc((size_t)Vn * Hn * 2, 8);

  k_zero<<<8, 1024, 0, stream>>>(flags, 257 * 32);
  k_all<<<G, BT, 0, stream>>>(enc, lens, emb, w_ih, w_hh, b_ih, b_hh,
                              attn_w, concat_w, gamma, beta, proj_w, out,
                              flags, go, h32, c32, awT, cwT, biasc,
                              amax, hh, hl, th, tl,
                              wch, wcl, ebh, ebl, pwh, pwl);
}